// Round 1
// 180.220 us; speedup vs baseline: 1.0152x; 1.0152x over previous
//
#include <hip/hip_runtime.h>
#include <hip/hip_bf16.h>

typedef __attribute__((ext_vector_type(8))) short bf16x8;
typedef __attribute__((ext_vector_type(4))) float f32x4;
typedef __attribute__((ext_vector_type(16))) float f32x16;
typedef __attribute__((ext_vector_type(2))) unsigned int u32x2;

#define S_LEN 2048
#define DMODEL 2048
#define NHEAD 32
#define NKVH 8
#define HDIM 64
#define EQKV 3072

#if defined(__has_builtin)
#if __has_builtin(__builtin_amdgcn_global_load_lds)
#define HAVE_GLL 1
#endif
#endif

__device__ __forceinline__ unsigned short f2bf(float f) {
  unsigned int u = __float_as_uint(f);
  u = (u + 0x7FFFu + ((u >> 16) & 1u)) >> 16;
  return (unsigned short)u;
}

__device__ __forceinline__ f32x4 mfma16(bf16x8 a, bf16x8 b, f32x4 c) {
  return __builtin_amdgcn_mfma_f32_16x16x32_bf16(a, b, c, 0, 0, 0);
}
__device__ __forceinline__ f32x16 mfma32(bf16x8 a, bf16x8 b, f32x16 c) {
  return __builtin_amdgcn_mfma_f32_32x32x16_bf16(a, b, c, 0, 0, 0);
}

__device__ __forceinline__ unsigned cvtpk(float a, float b) {
  unsigned r;
  asm("v_cvt_pk_bf16_f32 %0, %1, %2" : "=v"(r) : "v"(a), "v"(b));
  return r;
}

// lane l's upper/lower-32 exchange without the LDS path (T12 primitive).
__device__ __forceinline__ void plswap(unsigned& a, unsigned& b) {
  u32x2 r = __builtin_amdgcn_permlane32_swap(a, b, false, false);
  a = r.x;
  b = r.y;
}
__device__ __forceinline__ void plswapf(float& a, float& b) {
  unsigned ua = __float_as_uint(a), ub = __float_as_uint(b);
  plswap(ua, ub);
  a = __uint_as_float(ua);
  b = __uint_as_float(ub);
}

#if HAVE_GLL
__device__ __forceinline__ void gload16(const unsigned short* g,
                                        unsigned short* l) {
  __builtin_amdgcn_global_load_lds(
      (const __attribute__((address_space(1))) unsigned int*)g,
      (__attribute__((address_space(3))) unsigned int*)l, 16, 0, 0);
}
#endif

__global__ void cast_kernel(const float* __restrict__ src,
                            unsigned short* __restrict__ dst, int n4) {
  int i = blockIdx.x * blockDim.x + threadIdx.x;
  if (i >= n4) return;
  float4 v = ((const float4*)src)[i];
  ushort4 o;
  o.x = f2bf(v.x); o.y = f2bf(v.y); o.z = f2bf(v.z); o.w = f2bf(v.w);
  ((ushort4*)dst)[i] = o;
}

// C[M][N] = A[M][K] * B[N][K]^T, bf16 in, f32 out. 128x128 tile, 4 waves.
// Staging via global_load_lds w=16 (m97): linear LDS dest, source chunk
// pre-swizzled (^ row&7), reads apply the same XOR.
__launch_bounds__(256)
__global__ void gemm_bt(const unsigned short* __restrict__ A,
                        const unsigned short* __restrict__ B,
                        float* __restrict__ C, int M, int N, int K) {
  __shared__ unsigned short As[128 * 64];
  __shared__ unsigned short Bs[128 * 64];
  const int tid = threadIdx.x;
  const int w = tid >> 6, l = tid & 63;
  const int wr = w >> 1, wc = w & 1;
  const int bm = blockIdx.y, bn = blockIdx.x;
  const int lr = l & 15, lq = l >> 4;

  f32x4 acc[4][4];
#pragma unroll
  for (int m = 0; m < 4; ++m)
#pragma unroll
    for (int n = 0; n < 4; ++n) acc[m][n] = (f32x4)0.f;

  // per-issue global srcs (chunk c = i*256 + tid; row=c>>3, src=(c&7)^(row&7))
  const unsigned short* gA[4];
  const unsigned short* gB[4];
#pragma unroll
  for (int i = 0; i < 4; ++i) {
    int c = i * 256 + tid;
    int row = c >> 3;
    int sc = (c & 7) ^ (row & 7);
    gA[i] = A + (size_t)(bm * 128 + row) * K + sc * 8;
    gB[i] = B + (size_t)(bn * 128 + row) * K + sc * 8;
  }

  for (int k0 = 0; k0 < K; k0 += 64) {
#if HAVE_GLL
#pragma unroll
    for (int i = 0; i < 4; ++i) {
      gload16(gA[i] + k0, &As[(i * 256 + w * 64) * 8]);
      gload16(gB[i] + k0, &Bs[(i * 256 + w * 64) * 8]);
    }
#else
#pragma unroll
    for (int i = 0; i < 4; ++i) {
      int c = i * 256 + tid;
      *(uint4*)(&As[c * 8]) = *(const uint4*)(gA[i] + k0);
      *(uint4*)(&Bs[c * 8]) = *(const uint4*)(gB[i] + k0);
    }
#endif
    __syncthreads();
#pragma unroll
    for (int ks = 0; ks < 2; ++ks) {
      bf16x8 af[4], bfr[4];
#pragma unroll
      for (int m = 0; m < 4; ++m) {
        int row = wr * 64 + m * 16 + lr;
        int ch = (ks * 4 + lq) ^ (row & 7);
        af[m] = *(const bf16x8*)(&As[row * 64 + ch * 8]);
      }
#pragma unroll
      for (int n = 0; n < 4; ++n) {
        int row = wc * 64 + n * 16 + lr;
        int ch = (ks * 4 + lq) ^ (row & 7);
        bfr[n] = *(const bf16x8*)(&Bs[row * 64 + ch * 8]);
      }
#pragma unroll
      for (int m = 0; m < 4; ++m)
#pragma unroll
        for (int n = 0; n < 4; ++n)
          acc[m][n] = mfma16(af[m], bfr[n], acc[m][n]);
    }
    __syncthreads();
  }
  const int r0 = bm * 128 + wr * 64;
  const int c0 = bn * 128 + wc * 64;
#pragma unroll
  for (int m = 0; m < 4; ++m)
#pragma unroll
    for (int n = 0; n < 4; ++n)
#pragma unroll
      for (int r = 0; r < 4; ++r)
        C[(size_t)(r0 + m * 16 + 4 * lq + r) * N + c0 + n * 16 + lr] =
            acc[m][n][r];
}

// qkv f32 [S][3072] -> roped q bf16 [NH][S][64], roped k bf16 [NKV][S][64]
// K pre-scaled by (1/sqrt(64))*log2(e) so attn uses exp2 directly.
#define KSCALE 0.18033688011112042f
__global__ void rope_split(const float* __restrict__ qkv,
                           const float* __restrict__ cosb,
                           const float* __restrict__ sinb,
                           unsigned short* __restrict__ qb,
                           unsigned short* __restrict__ kbuf) {
  const int s = blockIdx.x;
  const float* row = qkv + (size_t)s * EQKV;
  for (int idx = threadIdx.x; idx < 1280; idx += 256) {
    int hh = idx >> 5;
    int m = idx & 31;
    float c = cosb[s * 32 + m];
    float sn = sinb[s * 32 + m];
    if (hh < 32) {
      float tr = row[hh * 64 + 2 * m];
      float ti = row[hh * 64 + 2 * m + 1];
      unsigned int pack = (unsigned int)f2bf(tr * c - ti * sn) |
                          ((unsigned int)f2bf(tr * sn + ti * c) << 16);
      *(unsigned int*)(qb + ((size_t)hh * S_LEN + s) * HDIM + 2 * m) = pack;
    } else {
      int kvh = hh - 32;
      float cs = c * KSCALE, ss = sn * KSCALE;
      float tr = row[2048 + kvh * 64 + 2 * m];
      float ti = row[2048 + kvh * 64 + 2 * m + 1];
      unsigned int pack = (unsigned int)f2bf(tr * cs - ti * ss) |
                          ((unsigned int)f2bf(tr * ss + ti * cs) << 16);
      *(unsigned int*)(kbuf + ((size_t)kvh * S_LEN + s) * HDIM + 2 * m) = pack;
    }
  }
}

// v slice of qkv -> vt[kvh][d][s] bf16 (transposed via LDS tile)
__global__ void v_transpose(const float* __restrict__ qkv,
                            unsigned short* __restrict__ vtb) {
  __shared__ unsigned short tile[64][72];
  const int kvh = blockIdx.x;
  const int st = blockIdx.y;
  const int t = threadIdx.x;
  {
    const int sl = t >> 2, dg = t & 3;
    const float* src =
        qkv + (size_t)(st * 64 + sl) * EQKV + 2560 + kvh * 64 + dg * 16;
#pragma unroll
    for (int j = 0; j < 16; ++j) tile[dg * 16 + j][sl] = f2bf(src[j]);
  }
  __syncthreads();
  {
    const int dl = t >> 2, sg = t & 3;
    unsigned short* dst =
        vtb + ((size_t)kvh * HDIM + dl) * S_LEN + st * 64 + sg * 16;
    *(uint4*)(dst) = *(const uint4*)(&tile[dl][sg * 16]);
    *(uint4*)(dst + 8) = *(const uint4*)(&tile[dl][sg * 16 + 8]);
  }
}

// Flash attention, swapped-operand 32x32 + 4-way split-K per block.
// Block = (head, 32 q-rows); wave wv handles KV tiles kt = wv, wv+4, ...
// v2 changes vs baseline (latency-bound per rocprof: MfmaUtil 8.6%,
// VALU 34%, HBM 3%):
//  - __launch_bounds__(256,4): VGPR cap 128 (same 16-wave/CU occupancy
//    band per m69's 64/128 steps) so K+V loads can all stay in flight.
//  - K/V loads hoisted to loop top: V's ~300cy L2 latency hides under
//    QK^T+softmax instead of stalling right before the PV MFMAs.
//  - T12: permlane32_swap replaces 10 __shfl_xor + 8 hi?: selects.
//  - T13: defer-max (THR=8 in log2 domain) skips the 32-mul O-rescale
//    + exp2 on tiles where the running max doesn't grow.
//  - T17: max3-friendly reduction tree (15 -> 8 ops).
//  - T5: s_setprio(1) around both MFMA clusters.
//  - LDS combine split into two 16-float phases: 40960 -> 19456 B/block
//    (stride 19 floats: 2-way bank aliasing only, which is free).
__launch_bounds__(256, 4)
__global__ void attn_kernel(const unsigned short* __restrict__ qb,
                            const unsigned short* __restrict__ kb,
                            const unsigned short* __restrict__ vtb,
                            unsigned short* __restrict__ aob) {
  __shared__ float buf[4][64][19];  // [wave][lane][o-half:16|m|l|pad]
  const int tid = threadIdx.x;
  const int wv = tid >> 6, l = tid & 63;
  const int bid = blockIdx.x;           // 2048 blocks
  const int h = bid & 31;
  const int qt = 63 - (bid >> 5);       // longest blocks first
  const int kvh = h >> 2;
  const int q0 = qt << 5;
  const int lq = l & 31;
  const int hi = l >> 5;
  const int qg = q0 + lq;

  const unsigned short* qrow = qb + ((size_t)h * S_LEN + qg) * HDIM + 8 * hi;
  bf16x8 qf[4];
#pragma unroll
  for (int j = 0; j < 4; ++j) qf[j] = *(const bf16x8*)(qrow + 16 * j);

  const unsigned short* kbase = kb + (size_t)kvh * S_LEN * HDIM;
  const unsigned short* vbase = vtb + (size_t)kvh * HDIM * S_LEN;

  f32x16 o0 = (f32x16)0.f, o1 = (f32x16)0.f;
  float mrun = -1e30f, lrun = 0.f;
  const int ntile = qt + 1;

  for (int kt = wv; kt < ntile; kt += 4) {
    const int key0 = kt << 5;
    // --- all global loads issued up front; latency hides under QK+softmax
    const unsigned short* krow = kbase + (size_t)(key0 + lq) * HDIM + 8 * hi;
    bf16x8 kf0 = *(const bf16x8*)(krow);
    bf16x8 kf1 = *(const bf16x8*)(krow + 16);
    bf16x8 kf2 = *(const bf16x8*)(krow + 32);
    bf16x8 kf3 = *(const bf16x8*)(krow + 48);
    const unsigned short* vrow0 = vbase + (size_t)lq * S_LEN + key0 + 8 * hi;
    const unsigned short* vrow1 = vrow0 + 32 * S_LEN;
    bf16x8 va00 = *(const bf16x8*)(vrow0);
    bf16x8 va01 = *(const bf16x8*)(vrow0 + 16);
    bf16x8 va10 = *(const bf16x8*)(vrow1);
    bf16x8 va11 = *(const bf16x8*)(vrow1 + 16);

    f32x16 s = (f32x16)0.f;
    __builtin_amdgcn_s_setprio(1);
    s = mfma32(kf0, qf[0], s);
    s = mfma32(kf1, qf[1], s);
    s = mfma32(kf2, qf[2], s);
    s = mfma32(kf3, qf[3], s);
    __builtin_amdgcn_s_setprio(0);

    float p[16];
    if (kt == ntile - 1) {  // diagonal tile: causal mask
#pragma unroll
      for (int r = 0; r < 16; ++r) {
        int key = key0 + (r & 3) + 8 * (r >> 2) + 4 * hi;
        p[r] = (key > qg) ? -1e30f : s[r];
      }
    } else {
#pragma unroll
      for (int r = 0; r < 16; ++r) p[r] = s[r];
    }
    // max tree, v_max3-fusable triples (T17)
    float a0 = fmaxf(fmaxf(p[0], p[1]), p[2]);
    float a1 = fmaxf(fmaxf(p[3], p[4]), p[5]);
    float a2 = fmaxf(fmaxf(p[6], p[7]), p[8]);
    float a3 = fmaxf(fmaxf(p[9], p[10]), p[11]);
    float a4 = fmaxf(fmaxf(p[12], p[13]), p[14]);
    float mt = fmaxf(fmaxf(fmaxf(a0, a1), a2), fmaxf(fmaxf(a3, a4), p[15]));
    float mto = mt;
    plswapf(mt, mto);
    mt = fmaxf(mt, mto);
    // T13 defer-max: only rescale when the max actually grew past THR=8
    // (log2 domain: P bounded by 2^8, safe in f32/bf16 accumulation).
    if (!__all(mt - mrun <= 8.f)) {
      float mnew = fmaxf(mrun, mt);
      float al = __builtin_amdgcn_exp2f(mrun - mnew);
      mrun = mnew;
      lrun *= al;
      o0 *= al;
      o1 *= al;
    }
#pragma unroll
    for (int r = 0; r < 16; ++r) p[r] = __builtin_amdgcn_exp2f(p[r] - mrun);
    float s0 = (p[0] + p[1]) + (p[2] + p[3]);
    float s1 = (p[4] + p[5]) + (p[6] + p[7]);
    float s2 = (p[8] + p[9]) + (p[10] + p[11]);
    float s3 = (p[12] + p[13]) + (p[14] + p[15]);
    float ts = (s0 + s1) + (s2 + s3);
    float tso = ts;
    plswapf(ts, tso);
    ts += tso;
    lrun += ts;
    // P -> bf16 B-fragments via cvt_pk + permlane32_swap (T12):
    // 8 cvt_pk + 4 swaps replace 8 cvt_pk + 8 shfl + 8 selects.
    union B8 { unsigned u[4]; bf16x8 v; } pb0, pb1;
    {
      unsigned t0 = cvtpk(p[0], p[1]), t1 = cvtpk(p[4], p[5]);
      plswap(t0, t1);
      pb0.u[0] = t0; pb0.u[2] = t1;
    }
    {
      unsigned t0 = cvtpk(p[2], p[3]), t1 = cvtpk(p[6], p[7]);
      plswap(t0, t1);
      pb0.u[1] = t0; pb0.u[3] = t1;
    }
    {
      unsigned t0 = cvtpk(p[8], p[9]), t1 = cvtpk(p[12], p[13]);
      plswap(t0, t1);
      pb1.u[0] = t0; pb1.u[2] = t1;
    }
    {
      unsigned t0 = cvtpk(p[10], p[11]), t1 = cvtpk(p[14], p[15]);
      plswap(t0, t1);
      pb1.u[1] = t0; pb1.u[3] = t1;
    }
    __builtin_amdgcn_s_setprio(1);
    o0 = mfma32(va00, pb0.v, o0);
    o0 = mfma32(va01, pb1.v, o0);
    o1 = mfma32(va10, pb0.v, o1);
    o1 = mfma32(va11, pb1.v, o1);
    __builtin_amdgcn_s_setprio(0);
  }

  // ---- two-phase split-K combine (o0 then o1, 19.4 KB LDS) ----
  // o-reg r of o{dh} maps to d = (r&3) + 8*(r>>2) + 4*hi + 32*dh;
  // wave wv combines regs [wv*4, wv*4+4) of each phase.
  {
    union F16 { f32x16 v; f32x4 q[4]; } uu;
    uu.v = o0;
    float* dst = &buf[wv][l][0];
#pragma unroll
    for (int i = 0; i < 4; ++i) *(f32x4*)(dst + 4 * i) = uu.q[i];
    dst[16] = mrun;
    dst[17] = lrun;
  }
  __syncthreads();
  float mfin = -1e30f;
#pragma unroll
  for (int w2 = 0; w2 < 4; ++w2) mfin = fmaxf(mfin, buf[w2][l][16]);
  float lsum = 0.f;
  float scl[4];
#pragma unroll
  for (int w2 = 0; w2 < 4; ++w2) {
    scl[w2] = __builtin_amdgcn_exp2f(buf[w2][l][16] - mfin);
    lsum += buf[w2][l][17] * scl[w2];
  }
  const float inv = 1.f / lsum;
  unsigned short* obase = aob + (size_t)qg * DMODEL + h * 64;
  {
    f32x4 acc = (f32x4)0.f;
#pragma unroll
    for (int w2 = 0; w2 < 4; ++w2)
      acc += *(const f32x4*)&buf[w2][l][wv * 4] * scl[w2];
    unsigned u0 = cvtpk(acc[0] * inv, acc[1] * inv);
    unsigned u1 = cvtpk(acc[2] * inv, acc[3] * inv);
    unsigned short* dsto = obase + 8 * wv + 4 * hi;
    *(unsigned*)(dsto) = u0;
    *(unsigned*)(dsto + 2) = u1;
  }
  __syncthreads();  // all phase-A reads done before overwrite
  {
    union F16 { f32x16 v; f32x4 q[4]; } uu;
    uu.v = o1;
    float* dst = &buf[wv][l][0];
#pragma unroll
    for (int i = 0; i < 4; ++i) *(f32x4*)(dst + 4 * i) = uu.q[i];
  }
  __syncthreads();
  {
    f32x4 acc = (f32x4)0.f;
#pragma unroll
    for (int w2 = 0; w2 < 4; ++w2)
      acc += *(const f32x4*)&buf[w2][l][wv * 4] * scl[w2];
    unsigned u0 = cvtpk(acc[0] * inv, acc[1] * inv);
    unsigned u1 = cvtpk(acc[2] * inv, acc[3] * inv);
    unsigned short* dsto = obase + 32 + 8 * wv + 4 * hi;
    *(unsigned*)(dsto) = u0;
    *(unsigned*)(dsto + 2) = u1;
  }
}

extern "C" void kernel_launch(void* const* d_in, const int* in_sizes, int n_in,
                              void* d_out, int out_size, void* d_ws,
                              size_t ws_size, hipStream_t stream) {
  const float* x = (const float*)d_in[0];
  const float* cosb = (const float*)d_in[1];
  const float* sinb = (const float*)d_in[2];
  const float* wqkv = (const float*)d_in[3];
  const float* wo = (const float*)d_in[4];
  float* out = (float*)d_out;
  char* ws = (char*)d_ws;
  float* qkv = (float*)(ws);                               // 25,165,824
  unsigned short* xb = (unsigned short*)(ws + 25165824);   //  8,388,608
  unsigned short* wb = (unsigned short*)(ws + 33554432);   // 12,582,912
  unsigned short* wob = (unsigned short*)(ws + 46137344);  //  8,388,608
  unsigned short* qb = (unsigned short*)(ws + 54525952);   //  8,388,608
  unsigned short* kbuf = (unsigned short*)(ws + 62914560); //  2,097,152
  unsigned short* vtb = (unsigned short*)(ws + 65011712);  //  2,097,152
  unsigned short* aob = (unsigned short*)(ws + 67108864);  //  8,388,608

  cast_kernel<<<dim3(1048576 / 256), 256, 0, stream>>>(x, xb, 1048576);
  cast_kernel<<<dim3(1572864 / 256), 256, 0, stream>>>(wqkv, wb, 1572864);
  cast_kernel<<<dim3(1048576 / 256), 256, 0, stream>>>(wo, wob, 1048576);
  gemm_bt<<<dim3(24, 16), 256, 0, stream>>>(xb, wb, qkv, 2048, 3072, 2048);
  rope_split<<<dim3(2048), 256, 0, stream>>>(qkv, cosb, sinb, qb, kbuf);
  v_transpose<<<dim3(8, 32), 256, 0, stream>>>(qkv, vtb);
  attn_kernel<<<dim3(2048), 256, 0, stream>>>(qb, kbuf, vtb, aob);
  gemm_bt<<<dim3(16, 16), 256, 0, stream>>>(aob, wob, out, 2048, 2048, 2048);
}

// Round 2
// 142.949 us; speedup vs baseline: 1.2799x; 1.2607x over previous
//
#include <hip/hip_runtime.h>
#include <hip/hip_bf16.h>

typedef __attribute__((ext_vector_type(8))) short bf16x8;
typedef __attribute__((ext_vector_type(4))) float f32x4;
typedef __attribute__((ext_vector_type(16))) float f32x16;
typedef __attribute__((ext_vector_type(2))) unsigned int u32x2;

#define S_LEN 2048
#define DMODEL 2048
#define NHEAD 32
#define NKVH 8
#define HDIM 64
#define EQKV 3072

#if defined(__has_builtin)
#if __has_builtin(__builtin_amdgcn_global_load_lds)
#define HAVE_GLL 1
#endif
#endif

__device__ __forceinline__ unsigned short f2bf(float f) {
  unsigned int u = __float_as_uint(f);
  u = (u + 0x7FFFu + ((u >> 16) & 1u)) >> 16;
  return (unsigned short)u;
}

__device__ __forceinline__ f32x4 mfma16(bf16x8 a, bf16x8 b, f32x4 c) {
  return __builtin_amdgcn_mfma_f32_16x16x32_bf16(a, b, c, 0, 0, 0);
}
__device__ __forceinline__ f32x16 mfma32(bf16x8 a, bf16x8 b, f32x16 c) {
  return __builtin_amdgcn_mfma_f32_32x32x16_bf16(a, b, c, 0, 0, 0);
}

__device__ __forceinline__ unsigned cvtpk(float a, float b) {
  unsigned r;
  asm("v_cvt_pk_bf16_f32 %0, %1, %2" : "=v"(r) : "v"(a), "v"(b));
  return r;
}

// lane l's upper/lower-32 exchange without the LDS path (T12 primitive).
__device__ __forceinline__ void plswap(unsigned& a, unsigned& b) {
  u32x2 r = __builtin_amdgcn_permlane32_swap(a, b, false, false);
  a = r.x;
  b = r.y;
}
__device__ __forceinline__ void plswapf(float& a, float& b) {
  unsigned ua = __float_as_uint(a), ub = __float_as_uint(b);
  plswap(ua, ub);
  a = __uint_as_float(ua);
  b = __uint_as_float(ub);
}

#if HAVE_GLL
__device__ __forceinline__ void gload16(const unsigned short* g,
                                        unsigned short* l) {
  __builtin_amdgcn_global_load_lds(
      (const __attribute__((address_space(1))) unsigned int*)g,
      (__attribute__((address_space(3))) unsigned int*)l, 16, 0, 0);
}
#endif

__global__ void cast_kernel(const float* __restrict__ src,
                            unsigned short* __restrict__ dst, int n4) {
  int i = blockIdx.x * blockDim.x + threadIdx.x;
  if (i >= n4) return;
  float4 v = ((const float4*)src)[i];
  ushort4 o;
  o.x = f2bf(v.x); o.y = f2bf(v.y); o.z = f2bf(v.z); o.w = f2bf(v.w);
  ((ushort4*)dst)[i] = o;
}

// C[M][N] = A[M][K] * B[N][K]^T, bf16 in, f32 out. 128x128 tile, 4 waves.
// Staging via global_load_lds w=16 (m97): linear LDS dest, source chunk
// pre-swizzled (^ row&7), reads apply the same XOR.
__launch_bounds__(256)
__global__ void gemm_bt(const unsigned short* __restrict__ A,
                        const unsigned short* __restrict__ B,
                        float* __restrict__ C, int M, int N, int K) {
  __shared__ unsigned short As[128 * 64];
  __shared__ unsigned short Bs[128 * 64];
  const int tid = threadIdx.x;
  const int w = tid >> 6, l = tid & 63;
  const int wr = w >> 1, wc = w & 1;
  const int bm = blockIdx.y, bn = blockIdx.x;
  const int lr = l & 15, lq = l >> 4;

  f32x4 acc[4][4];
#pragma unroll
  for (int m = 0; m < 4; ++m)
#pragma unroll
    for (int n = 0; n < 4; ++n) acc[m][n] = (f32x4)0.f;

  // per-issue global srcs (chunk c = i*256 + tid; row=c>>3, src=(c&7)^(row&7))
  const unsigned short* gA[4];
  const unsigned short* gB[4];
#pragma unroll
  for (int i = 0; i < 4; ++i) {
    int c = i * 256 + tid;
    int row = c >> 3;
    int sc = (c & 7) ^ (row & 7);
    gA[i] = A + (size_t)(bm * 128 + row) * K + sc * 8;
    gB[i] = B + (size_t)(bn * 128 + row) * K + sc * 8;
  }

  for (int k0 = 0; k0 < K; k0 += 64) {
#if HAVE_GLL
#pragma unroll
    for (int i = 0; i < 4; ++i) {
      gload16(gA[i] + k0, &As[(i * 256 + w * 64) * 8]);
      gload16(gB[i] + k0, &Bs[(i * 256 + w * 64) * 8]);
    }
#else
#pragma unroll
    for (int i = 0; i < 4; ++i) {
      int c = i * 256 + tid;
      *(uint4*)(&As[c * 8]) = *(const uint4*)(gA[i] + k0);
      *(uint4*)(&Bs[c * 8]) = *(const uint4*)(gB[i] + k0);
    }
#endif
    __syncthreads();
#pragma unroll
    for (int ks = 0; ks < 2; ++ks) {
      bf16x8 af[4], bfr[4];
#pragma unroll
      for (int m = 0; m < 4; ++m) {
        int row = wr * 64 + m * 16 + lr;
        int ch = (ks * 4 + lq) ^ (row & 7);
        af[m] = *(const bf16x8*)(&As[row * 64 + ch * 8]);
      }
#pragma unroll
      for (int n = 0; n < 4; ++n) {
        int row = wc * 64 + n * 16 + lr;
        int ch = (ks * 4 + lq) ^ (row & 7);
        bfr[n] = *(const bf16x8*)(&Bs[row * 64 + ch * 8]);
      }
#pragma unroll
      for (int m = 0; m < 4; ++m)
#pragma unroll
        for (int n = 0; n < 4; ++n)
          acc[m][n] = mfma16(af[m], bfr[n], acc[m][n]);
    }
    __syncthreads();
  }
  const int r0 = bm * 128 + wr * 64;
  const int c0 = bn * 128 + wc * 64;
#pragma unroll
  for (int m = 0; m < 4; ++m)
#pragma unroll
    for (int n = 0; n < 4; ++n)
#pragma unroll
      for (int r = 0; r < 4; ++r)
        C[(size_t)(r0 + m * 16 + 4 * lq + r) * N + c0 + n * 16 + lr] =
            acc[m][n][r];
}

// qkv f32 [S][3072] -> roped q bf16 [NH][S][64] (natural layout) and
// roped k bf16 in MFMA-FRAGMENT-TILED layout:
//   kft[kvh][kt][j][lane]*8 shorts, lane = (key&31) + 32*hi,
//   holding K[kt*32 + (key&31)][16j + 8hi + 0..7]
// so attn's kf_j load is lane-contiguous (fully coalesced 1KB/instr).
// K pre-scaled by (1/sqrt(64))*log2(e) so attn uses exp2 directly.
#define KSCALE 0.18033688011112042f
__global__ void rope_split(const float* __restrict__ qkv,
                           const float* __restrict__ cosb,
                           const float* __restrict__ sinb,
                           unsigned short* __restrict__ qb,
                           unsigned short* __restrict__ kft) {
  const int s = blockIdx.x;
  const float* row = qkv + (size_t)s * EQKV;
  for (int idx = threadIdx.x; idx < 1280; idx += 256) {
    int hh = idx >> 5;
    int m = idx & 31;
    float c = cosb[s * 32 + m];
    float sn = sinb[s * 32 + m];
    if (hh < 32) {
      float tr = row[hh * 64 + 2 * m];
      float ti = row[hh * 64 + 2 * m + 1];
      unsigned int pack = (unsigned int)f2bf(tr * c - ti * sn) |
                          ((unsigned int)f2bf(tr * sn + ti * c) << 16);
      *(unsigned int*)(qb + ((size_t)hh * S_LEN + s) * HDIM + 2 * m) = pack;
    } else {
      int kvh = hh - 32;
      float cs = c * KSCALE, ss = sn * KSCALE;
      float tr = row[2048 + kvh * 64 + 2 * m];
      float ti = row[2048 + kvh * 64 + 2 * m + 1];
      unsigned int pack = (unsigned int)f2bf(tr * cs - ti * ss) |
                          ((unsigned int)f2bf(tr * ss + ti * cs) << 16);
      // d = 2m: j = m>>3, hi = (m>>2)&1, short-offset in chunk = (m&3)*2
      int kt = s >> 5, lq = s & 31;
      int j = m >> 3, hi = (m >> 2) & 1;
      unsigned short* dst =
          kft +
          ((((size_t)kvh * 64 + kt) * 4 + j) * 64 + lq + 32 * hi) * 8 +
          (m & 3) * 2;
      *(unsigned int*)dst = pack;
    }
  }
}

// v slice of qkv -> V^T in MFMA-FRAGMENT-TILED layout:
//   vft[kvh][kt][c][lane]*8 shorts, lane = lq + 32*hi,
//   c0/c1: d = lq     (-> o0), keys kt*32 + (c&1)*16 + 8hi + 0..7
//   c2/c3: d = lq+32  (-> o1), same key mapping.
// attn's va loads become lane-contiguous (fully coalesced 1KB/instr).
__global__ void v_transpose(const float* __restrict__ qkv,
                            unsigned short* __restrict__ vft) {
  __shared__ unsigned short tile[64][72];
  const int kvh = blockIdx.x;
  const int st = blockIdx.y;  // 64-key window -> 2 kt tiles
  const int t = threadIdx.x;
  {
    const int sl = t >> 2, dg = t & 3;
    const float* src =
        qkv + (size_t)(st * 64 + sl) * EQKV + 2560 + kvh * 64 + dg * 16;
#pragma unroll
    for (int j = 0; j < 16; ++j) tile[dg * 16 + j][sl] = f2bf(src[j]);
  }
  __syncthreads();
  {
    const int kt_local = t >> 7, c = (t >> 5) & 3, lq2 = t & 31;
    const int kt = st * 2 + kt_local;
    const int d = ((c >> 1) & 1) * 32 + lq2;
    unsigned short* dbase =
        vft + (((size_t)(kvh * 64 + kt) * 4 + c) * 64) * 8;
#pragma unroll
    for (int hi2 = 0; hi2 < 2; ++hi2) {
      int koff = kt_local * 32 + (c & 1) * 16 + 8 * hi2;
      *(uint4*)(dbase + (lq2 + 32 * hi2) * 8) =
          *(const uint4*)(&tile[d][koff]);
    }
  }
}

// Flash attention, swapped-operand 32x32 + 4-way split-K per block.
// Block = (head, 32 q-rows); wave wv handles KV tiles kt = wv, wv+4, ...
// v3 change (rocprof: MfmaUtil stuck at 8.9% while VALUBusy halved ->
// vector-memory address divergence was the stall): K and V^T now live in
// fragment-tiled buffers, so all 8 per-tile loads are contiguous 1KB
// (16 lines/instr vs 64 for the old V^T reads / 32 for K).
__launch_bounds__(256, 4)
__global__ void attn_kernel(const unsigned short* __restrict__ qb,
                            const unsigned short* __restrict__ kft,
                            const unsigned short* __restrict__ vft,
                            unsigned short* __restrict__ aob) {
  __shared__ float buf[4][64][19];  // [wave][lane][o-half:16|m|l|pad]
  const int tid = threadIdx.x;
  const int wv = tid >> 6, l = tid & 63;
  const int bid = blockIdx.x;           // 2048 blocks
  const int h = bid & 31;
  const int qt = 63 - (bid >> 5);       // longest blocks first
  const int kvh = h >> 2;
  const int q0 = qt << 5;
  const int lq = l & 31;
  const int hi = l >> 5;
  const int qg = q0 + lq;

  const unsigned short* qrow = qb + ((size_t)h * S_LEN + qg) * HDIM + 8 * hi;
  bf16x8 qf[4];
#pragma unroll
  for (int j = 0; j < 4; ++j) qf[j] = *(const bf16x8*)(qrow + 16 * j);

  const unsigned short* kbase = kft + (size_t)kvh * 64 * 2048;
  const unsigned short* vbase = vft + (size_t)kvh * 64 * 2048;

  f32x16 o0 = (f32x16)0.f, o1 = (f32x16)0.f;
  float mrun = -1e30f, lrun = 0.f;
  const int ntile = qt + 1;

  for (int kt = wv; kt < ntile; kt += 4) {
    const int key0 = kt << 5;
    // --- all global loads issued up front, each fully coalesced (1KB)
    const unsigned short* kvt = kbase + (size_t)kt * 2048;
    bf16x8 kf0 = *(const bf16x8*)(kvt + l * 8);
    bf16x8 kf1 = *(const bf16x8*)(kvt + 512 + l * 8);
    bf16x8 kf2 = *(const bf16x8*)(kvt + 1024 + l * 8);
    bf16x8 kf3 = *(const bf16x8*)(kvt + 1536 + l * 8);
    const unsigned short* vvt = vbase + (size_t)kt * 2048;
    bf16x8 va00 = *(const bf16x8*)(vvt + l * 8);
    bf16x8 va01 = *(const bf16x8*)(vvt + 512 + l * 8);
    bf16x8 va10 = *(const bf16x8*)(vvt + 1024 + l * 8);
    bf16x8 va11 = *(const bf16x8*)(vvt + 1536 + l * 8);

    f32x16 s = (f32x16)0.f;
    __builtin_amdgcn_s_setprio(1);
    s = mfma32(kf0, qf[0], s);
    s = mfma32(kf1, qf[1], s);
    s = mfma32(kf2, qf[2], s);
    s = mfma32(kf3, qf[3], s);
    __builtin_amdgcn_s_setprio(0);

    float p[16];
    if (kt == ntile - 1) {  // diagonal tile: causal mask
#pragma unroll
      for (int r = 0; r < 16; ++r) {
        int key = key0 + (r & 3) + 8 * (r >> 2) + 4 * hi;
        p[r] = (key > qg) ? -1e30f : s[r];
      }
    } else {
#pragma unroll
      for (int r = 0; r < 16; ++r) p[r] = s[r];
    }
    // max tree, v_max3-fusable triples (T17)
    float a0 = fmaxf(fmaxf(p[0], p[1]), p[2]);
    float a1 = fmaxf(fmaxf(p[3], p[4]), p[5]);
    float a2 = fmaxf(fmaxf(p[6], p[7]), p[8]);
    float a3 = fmaxf(fmaxf(p[9], p[10]), p[11]);
    float a4 = fmaxf(fmaxf(p[12], p[13]), p[14]);
    float mt = fmaxf(fmaxf(fmaxf(a0, a1), a2), fmaxf(fmaxf(a3, a4), p[15]));
    float mto = mt;
    plswapf(mt, mto);
    mt = fmaxf(mt, mto);
    // T13 defer-max: only rescale when the max actually grew past THR=8
    // (log2 domain: P bounded by 2^8, safe in f32/bf16 accumulation).
    if (!__all(mt - mrun <= 8.f)) {
      float mnew = fmaxf(mrun, mt);
      float al = __builtin_amdgcn_exp2f(mrun - mnew);
      mrun = mnew;
      lrun *= al;
      o0 *= al;
      o1 *= al;
    }
#pragma unroll
    for (int r = 0; r < 16; ++r) p[r] = __builtin_amdgcn_exp2f(p[r] - mrun);
    float s0 = (p[0] + p[1]) + (p[2] + p[3]);
    float s1 = (p[4] + p[5]) + (p[6] + p[7]);
    float s2 = (p[8] + p[9]) + (p[10] + p[11]);
    float s3 = (p[12] + p[13]) + (p[14] + p[15]);
    float ts = (s0 + s1) + (s2 + s3);
    float tso = ts;
    plswapf(ts, tso);
    ts += tso;
    lrun += ts;
    // P -> bf16 B-fragments via cvt_pk + permlane32_swap (T12).
    union B8 { unsigned u[4]; bf16x8 v; } pb0, pb1;
    {
      unsigned t0 = cvtpk(p[0], p[1]), t1 = cvtpk(p[4], p[5]);
      plswap(t0, t1);
      pb0.u[0] = t0; pb0.u[2] = t1;
    }
    {
      unsigned t0 = cvtpk(p[2], p[3]), t1 = cvtpk(p[6], p[7]);
      plswap(t0, t1);
      pb0.u[1] = t0; pb0.u[3] = t1;
    }
    {
      unsigned t0 = cvtpk(p[8], p[9]), t1 = cvtpk(p[12], p[13]);
      plswap(t0, t1);
      pb1.u[0] = t0; pb1.u[2] = t1;
    }
    {
      unsigned t0 = cvtpk(p[10], p[11]), t1 = cvtpk(p[14], p[15]);
      plswap(t0, t1);
      pb1.u[1] = t0; pb1.u[3] = t1;
    }
    __builtin_amdgcn_s_setprio(1);
    o0 = mfma32(va00, pb0.v, o0);
    o0 = mfma32(va01, pb1.v, o0);
    o1 = mfma32(va10, pb0.v, o1);
    o1 = mfma32(va11, pb1.v, o1);
    __builtin_amdgcn_s_setprio(0);
  }

  // ---- two-phase split-K combine (o0 then o1, 19.4 KB LDS) ----
  // o-reg r of o{dh} maps to d = (r&3) + 8*(r>>2) + 4*hi + 32*dh;
  // wave wv combines regs [wv*4, wv*4+4) of each phase.
  {
    union F16 { f32x16 v; f32x4 q[4]; } uu;
    uu.v = o0;
    float* dst = &buf[wv][l][0];
#pragma unroll
    for (int i = 0; i < 4; ++i) *(f32x4*)(dst + 4 * i) = uu.q[i];
    dst[16] = mrun;
    dst[17] = lrun;
  }
  __syncthreads();
  float mfin = -1e30f;
#pragma unroll
  for (int w2 = 0; w2 < 4; ++w2) mfin = fmaxf(mfin, buf[w2][l][16]);
  float lsum = 0.f;
  float scl[4];
#pragma unroll
  for (int w2 = 0; w2 < 4; ++w2) {
    scl[w2] = __builtin_amdgcn_exp2f(buf[w2][l][16] - mfin);
    lsum += buf[w2][l][17] * scl[w2];
  }
  const float inv = 1.f / lsum;
  unsigned short* obase = aob + (size_t)qg * DMODEL + h * 64;
  {
    f32x4 acc = (f32x4)0.f;
#pragma unroll
    for (int w2 = 0; w2 < 4; ++w2)
      acc += *(const f32x4*)&buf[w2][l][wv * 4] * scl[w2];
    unsigned u0 = cvtpk(acc[0] * inv, acc[1] * inv);
    unsigned u1 = cvtpk(acc[2] * inv, acc[3] * inv);
    unsigned short* dsto = obase + 8 * wv + 4 * hi;
    *(unsigned*)(dsto) = u0;
    *(unsigned*)(dsto + 2) = u1;
  }
  __syncthreads();  // all phase-A reads done before overwrite
  {
    union F16 { f32x16 v; f32x4 q[4]; } uu;
    uu.v = o1;
    float* dst = &buf[wv][l][0];
#pragma unroll
    for (int i = 0; i < 4; ++i) *(f32x4*)(dst + 4 * i) = uu.q[i];
  }
  __syncthreads();
  {
    f32x4 acc = (f32x4)0.f;
#pragma unroll
    for (int w2 = 0; w2 < 4; ++w2)
      acc += *(const f32x4*)&buf[w2][l][wv * 4] * scl[w2];
    unsigned u0 = cvtpk(acc[0] * inv, acc[1] * inv);
    unsigned u1 = cvtpk(acc[2] * inv, acc[3] * inv);
    unsigned short* dsto = obase + 32 + 8 * wv + 4 * hi;
    *(unsigned*)(dsto) = u0;
    *(unsigned*)(dsto + 2) = u1;
  }
}

extern "C" void kernel_launch(void* const* d_in, const int* in_sizes, int n_in,
                              void* d_out, int out_size, void* d_ws,
                              size_t ws_size, hipStream_t stream) {
  const float* x = (const float*)d_in[0];
  const float* cosb = (const float*)d_in[1];
  const float* sinb = (const float*)d_in[2];
  const float* wqkv = (const float*)d_in[3];
  const float* wo = (const float*)d_in[4];
  float* out = (float*)d_out;
  char* ws = (char*)d_ws;
  float* qkv = (float*)(ws);                               // 25,165,824
  unsigned short* xb = (unsigned short*)(ws + 25165824);   //  8,388,608
  unsigned short* wb = (unsigned short*)(ws + 33554432);   // 12,582,912
  unsigned short* wob = (unsigned short*)(ws + 46137344);  //  8,388,608
  unsigned short* qb = (unsigned short*)(ws + 54525952);   //  8,388,608
  unsigned short* kft = (unsigned short*)(ws + 62914560);  //  2,097,152
  unsigned short* vft = (unsigned short*)(ws + 65011712);  //  2,097,152
  unsigned short* aob = (unsigned short*)(ws + 67108864);  //  8,388,608

  cast_kernel<<<dim3(1048576 / 256), 256, 0, stream>>>(x, xb, 1048576);
  cast_kernel<<<dim3(1572864 / 256), 256, 0, stream>>>(wqkv, wb, 1572864);
  cast_kernel<<<dim3(1048576 / 256), 256, 0, stream>>>(wo, wob, 1048576);
  gemm_bt<<<dim3(24, 16), 256, 0, stream>>>(xb, wb, qkv, 2048, 3072, 2048);
  rope_split<<<dim3(2048), 256, 0, stream>>>(qkv, cosb, sinb, qb, kft);
  v_transpose<<<dim3(8, 32), 256, 0, stream>>>(qkv, vft);
  attn_kernel<<<dim3(2048), 256, 0, stream>>>(qb, kft, vft, aob);
  gemm_bt<<<dim3(16, 16), 256, 0, stream>>>(aob, wob, out, 2048, 2048, 2048);
}